// Round 2
// baseline (208.564 us; speedup 1.0000x reference)
//
#include <hip/hip_runtime.h>
#include <cstdint>

typedef __bf16 bf16_t;
typedef __bf16 bf16x8 __attribute__((ext_vector_type(8)));
typedef float  f32x4  __attribute__((ext_vector_type(4)));

// Workspace layout
#define XPAD_ELEMS (32UL*58*58*128)      // padded NHWC bf16 input
#define WPERM_OFF  (XPAD_ELEMS*2)        // bytes (27,557,888 — 256B aligned)
#define WPERM_ELEMS (256UL*9*128)
#define WS_NEEDED  (WPERM_OFF + WPERM_ELEMS*2)

// ---------------- zero the padded input (borders must be 0) ----------------
__global__ void k_zero(uint4* __restrict__ p, int n4) {
  uint4 z; z.x = z.y = z.z = z.w = 0;
  for (int i = blockIdx.x * blockDim.x + threadIdx.x; i < n4; i += gridDim.x * blockDim.x)
    p[i] = z;
}

// ------- transpose+convert x: NCHW f32 -> padded NHWC bf16 (32,58,58,128) -------
__global__ __launch_bounds__(256) void k_xform(const float* __restrict__ x, bf16_t* __restrict__ Xp) {
  __shared__ float lds[128 * 57];          // [c][w], pad 57 to kill bank conflicts
  const int b = blockIdx.x;
  const int n = b / 56, h = b % 56;
  const float* src = x + (size_t)n * 401408 + h * 56;   // + c*3136 + w
  const int t = threadIdx.x;
  for (int i = t; i < 7168; i += 256) {    // 128 c * 56 w
    int c = i / 56;
    int w = i - c * 56;
    lds[c * 57 + w] = src[(size_t)c * 3136 + w];
  }
  __syncthreads();
  bf16_t* dst = Xp + ((size_t)(n * 58 + h + 1) * 58 + 1) * 128;  // + w*128 + c
  for (int i = t; i < 3584; i += 256) {    // pairs of channels
    int cp = i & 63, w = i >> 6;
    int c0 = cp * 2;
    unsigned short u0 = __builtin_bit_cast(unsigned short, (bf16_t)lds[c0 * 57 + w]);
    unsigned short u1 = __builtin_bit_cast(unsigned short, (bf16_t)lds[(c0 + 1) * 57 + w]);
    *(unsigned int*)(dst + (size_t)w * 128 + c0) = (unsigned)u0 | ((unsigned)u1 << 16);
  }
}

// ------- weight permute: OIHW (256,128,3,3) f32 -> (256, 9, 128) bf16 -------
__global__ void k_wperm(const float* __restrict__ wt, bf16_t* __restrict__ Wp) {
  int i = blockIdx.x * 256 + threadIdx.x;
  if (i >= 294912) return;
  int k = i / 1152;
  int rem = i - k * 1152;
  int rs = rem >> 7;
  int c = rem & 127;
  Wp[i] = (bf16_t)wt[k * 1152 + c * 9 + rs];
}

// ---------------- naive fp32 fallback (only if ws too small) ----------------
__global__ void k_naive(const float* __restrict__ x, const float* __restrict__ wt,
                        const float* __restrict__ bs, float* __restrict__ out) {
  int idx = blockIdx.x * 256 + threadIdx.x;
  if (idx >= 25690112) return;
  int w = idx % 56; int tmp = idx / 56;
  int h = tmp % 56; tmp /= 56;
  int k = tmp % 256; int n = tmp / 256;
  float acc = bs[k];
  for (int c = 0; c < 128; ++c)
    for (int r = 0; r < 3; ++r) {
      int hy = h + r - 1; if ((unsigned)hy >= 56u) continue;
      for (int s = 0; s < 3; ++s) {
        int wx = w + s - 1; if ((unsigned)wx >= 56u) continue;
        acc += x[((size_t)(n * 128 + c) * 56 + hy) * 56 + wx] *
               wt[((size_t)(k * 128 + c) * 3 + r) * 3 + s];
      }
    }
  out[idx] = acc;
}

// ---------------- main implicit-GEMM MFMA conv ----------------
// A = Wperm (256 x 1152), B = im2col(Xpad) (1152 x 100352), reduce order ck = rs*128 + c.
// Per K-step of 32: rs = t>>2 fixed, c0 = (t&3)*32.
#define BOFF(t) ((((((t) >> 2)) / 3) * 58 + (((t) >> 2) % 3)) * 128 + ((t) & 3) * 32)

__global__ __launch_bounds__(256) void k_conv(const bf16_t* __restrict__ Xp,
                                              const bf16_t* __restrict__ Wp,
                                              const float* __restrict__ bias,
                                              float* __restrict__ out) {
  // B tile double-buffered: [buf][kc(=k/8)][n][8] -> stride-16B per 16-lane group, conflict-free
  __shared__ bf16_t Blds[2][4][128][8];
  const int tid = threadIdx.x;
  const int lane = tid & 63;
  const int wave = tid >> 6;
  const int m0 = ((int)blockIdx.x & 1) * 128;
  const int p0 = ((int)blockIdx.x >> 1) * 128;
  const int wr = wave >> 1, wc = wave & 1;

  // --- B staging mapping: thread -> (n = tid&127, kc = tid>>7 and +2)
  const int sn = tid & 127;
  const int skc = tid >> 7;     // 0 or 1; second chunk uses skc+2
  const int pp = p0 + sn;
  const int nimg = pp / 3136;
  const int hwp = pp - nimg * 3136;
  const int hh = hwp / 56;
  const int ww = hwp - hh * 56;
  const bf16_t* xb = Xp + (((size_t)nimg * 58 + hh) * 58 + ww) * 128 + skc * 8;

  // --- A fragments loaded directly from L2-resident Wperm
  const int arow = m0 + wr * 64 + (lane & 15);
  const bf16_t* wb = Wp + (size_t)arow * 1152 + (lane >> 4) * 8;

  f32x4 acc[4][4] = {};
  bf16x8 a_cur[4], a_next[4], breg0, breg1;

  // prologue: stage t=0, prefetch t=1 (B) and t=0 (A)
  breg0 = *(const bf16x8*)(xb + BOFF(0));
  breg1 = *(const bf16x8*)(xb + BOFF(0) + 16);
#pragma unroll
  for (int mi = 0; mi < 4; ++mi) a_cur[mi] = *(const bf16x8*)(wb + mi * 18432);
  *(bf16x8*)&Blds[0][skc][sn][0]     = breg0;
  *(bf16x8*)&Blds[0][skc + 2][sn][0] = breg1;
  breg0 = *(const bf16x8*)(xb + BOFF(1));
  breg1 = *(const bf16x8*)(xb + BOFF(1) + 16);
  __syncthreads();

#pragma unroll
  for (int t = 0; t < 36; ++t) {
    const int cur = t & 1;
    const int nxt = cur ^ 1;
    // fragment reads: lane holds B[k=(l>>4)*8+j][n = wc*64+ni*16+(l&15)]
    bf16x8 bfr[4];
#pragma unroll
    for (int ni = 0; ni < 4; ++ni)
      bfr[ni] = *(const bf16x8*)&Blds[cur][lane >> 4][wc * 64 + ni * 16 + (lane & 15)][0];
    // write staged regs (data for t+1) into the other buffer
    if (t + 1 < 36) {
      *(bf16x8*)&Blds[nxt][skc][sn][0]     = breg0;
      *(bf16x8*)&Blds[nxt][skc + 2][sn][0] = breg1;
    }
    // issue global loads for t+2 (B) and t+1 (A) — hide latency under MFMA
    if (t + 2 < 36) {
      breg0 = *(const bf16x8*)(xb + BOFF(t + 2));
      breg1 = *(const bf16x8*)(xb + BOFF(t + 2) + 16);
    }
    if (t + 1 < 36) {
#pragma unroll
      for (int mi = 0; mi < 4; ++mi)
        a_next[mi] = *(const bf16x8*)(wb + mi * 18432 + (t + 1) * 32);
    }
#pragma unroll
    for (int mi = 0; mi < 4; ++mi)
#pragma unroll
      for (int ni = 0; ni < 4; ++ni)
        acc[mi][ni] = __builtin_amdgcn_mfma_f32_16x16x32_bf16(a_cur[mi], bfr[ni], acc[mi][ni], 0, 0, 0);
    if (t + 1 < 36) {
#pragma unroll
      for (int mi = 0; mi < 4; ++mi) a_cur[mi] = a_next[mi];
    }
    __syncthreads();
  }

  // epilogue: D[row][col]: reg j of lane -> row=(l>>4)*4+j, col=l&15 (verified layout)
  float bv[4][4];
#pragma unroll
  for (int mi = 0; mi < 4; ++mi)
#pragma unroll
    for (int j = 0; j < 4; ++j)
      bv[mi][j] = bias[m0 + wr * 64 + mi * 16 + (lane >> 4) * 4 + j];

#pragma unroll
  for (int ni = 0; ni < 4; ++ni) {
    int p = p0 + wc * 64 + ni * 16 + (lane & 15);
    int nim = p / 3136;
    int hw2 = p - nim * 3136;
    float* ob = out + (size_t)nim * 802816 + hw2;
#pragma unroll
    for (int mi = 0; mi < 4; ++mi) {
      int rowb = m0 + wr * 64 + mi * 16 + (lane >> 4) * 4;
#pragma unroll
      for (int j = 0; j < 4; ++j)
        ob[(size_t)(rowb + j) * 3136] = acc[mi][ni][j] + bv[mi][j];
    }
  }
}

extern "C" void kernel_launch(void* const* d_in, const int* in_sizes, int n_in,
                              void* d_out, int out_size, void* d_ws, size_t ws_size,
                              hipStream_t stream) {
  const float* x  = (const float*)d_in[0];
  const float* wt = (const float*)d_in[1];
  const float* bs = (const float*)d_in[2];
  float* out = (float*)d_out;

  if (ws_size < WS_NEEDED) {     // safety net: direct fp32 conv
    k_naive<<<(25690112 + 255) / 256, 256, 0, stream>>>(x, wt, bs, out);
    return;
  }

  bf16_t* Xp = (bf16_t*)d_ws;
  bf16_t* Wp = (bf16_t*)((char*)d_ws + WPERM_OFF);

  k_zero <<<2048, 256, 0, stream>>>((uint4*)d_ws, (int)(XPAD_ELEMS * 2 / 16));
  k_xform<<<1792, 256, 0, stream>>>(x, Xp);                 // 32*56 blocks
  k_wperm<<<1152, 256, 0, stream>>>(wt, Wp);                // 294912 / 256
  k_conv <<<1568, 256, 0, stream>>>(Xp, Wp, bs, out);       // 2 m-tiles * 784 n-tiles
}

// Round 3
// 158.086 us; speedup vs baseline: 1.3193x; 1.3193x over previous
//
#include <hip/hip_runtime.h>
#include <cstdint>

typedef __bf16 bf16_t;
typedef __bf16 bf16x8 __attribute__((ext_vector_type(8)));
typedef float  f32x4  __attribute__((ext_vector_type(4)));

// Workspace layout
#define XPAD_ELEMS (32UL*58*58*128)      // padded NHWC bf16 input
#define WPERM_OFF  (XPAD_ELEMS*2)        // bytes (27,557,888 — 256B aligned)
#define WPERM_ELEMS (256UL*9*128)
#define WS_NEEDED  (WPERM_OFF + WPERM_ELEMS*2)

// async global->LDS, 16B per lane; lds dest is wave-uniform base + lane*16
__device__ __forceinline__ void async16(const bf16_t* g, bf16_t* l) {
  __builtin_amdgcn_global_load_lds(
      (const __attribute__((address_space(1))) void*)g,
      (__attribute__((address_space(3))) void*)l, 16, 0, 0);
}

// ------- transpose+convert x: NCHW f32 -> padded NHWC bf16 (32,58,58,128) -------
// Border zeroing fused in: blocks cover all 58 padded rows; border rows/pixels zeroed.
__global__ __launch_bounds__(256) void k_xform(const float* __restrict__ x, bf16_t* __restrict__ Xp) {
  const int b = blockIdx.x;
  const int n = b / 58, hp = b % 58;
  bf16_t* drow = Xp + ((size_t)n * 58 + hp) * 58 * 128;
  const int t = threadIdx.x;
  uint4 z; z.x = z.y = z.z = z.w = 0;
  if (hp == 0 || hp == 57) {             // full border row: 58*128 bf16 = 928 uint4
    uint4* p = (uint4*)drow;
    for (int i = t; i < 928; i += 256) p[i] = z;
    return;
  }
  if (t < 32) {                           // border pixels w=0 and w=57 (16 uint4 each)
    uint4* p0 = (uint4*)drow;
    uint4* p1 = (uint4*)(drow + 57 * 128);
    if (t < 16) p0[t] = z; else p1[t - 16] = z;
  }
  const int h = hp - 1;
  const float* src = x + (size_t)n * 401408 + h * 56;   // + c*3136 + w
  __shared__ float lds[128 * 57];
  for (int i = t; i < 7168; i += 256) {   // 128 c * 56 w
    int c = i / 56;
    int w = i - c * 56;
    lds[c * 57 + w] = src[(size_t)c * 3136 + w];
  }
  __syncthreads();
  bf16_t* dst = drow + 128;               // w starts at 1
  for (int i = t; i < 3584; i += 256) {   // pairs of channels
    int cp = i & 63, w = i >> 6;
    int c0 = cp * 2;
    unsigned short u0 = __builtin_bit_cast(unsigned short, (bf16_t)lds[c0 * 57 + w]);
    unsigned short u1 = __builtin_bit_cast(unsigned short, (bf16_t)lds[(c0 + 1) * 57 + w]);
    *(unsigned int*)(dst + (size_t)w * 128 + c0) = (unsigned)u0 | ((unsigned)u1 << 16);
  }
}

// ------- weight permute: OIHW (256,128,3,3) f32 -> (256, 9, 128) bf16 -------
__global__ void k_wperm(const float* __restrict__ wt, bf16_t* __restrict__ Wp) {
  int i = blockIdx.x * 256 + threadIdx.x;
  if (i >= 294912) return;
  int k = i / 1152;
  int rem = i - k * 1152;
  int rs = rem >> 7;
  int c = rem & 127;
  Wp[i] = (bf16_t)wt[k * 1152 + c * 9 + rs];
}

// ---------------- naive fp32 fallback (only if ws too small) ----------------
__global__ void k_naive(const float* __restrict__ x, const float* __restrict__ wt,
                        const float* __restrict__ bs, float* __restrict__ out) {
  int idx = blockIdx.x * 256 + threadIdx.x;
  if (idx >= 25690112) return;
  int w = idx % 56; int tmp = idx / 56;
  int h = tmp % 56; tmp /= 56;
  int k = tmp % 256; int n = tmp / 256;
  float acc = bs[k];
  for (int c = 0; c < 128; ++c)
    for (int r = 0; r < 3; ++r) {
      int hy = h + r - 1; if ((unsigned)hy >= 56u) continue;
      for (int s = 0; s < 3; ++s) {
        int wx = w + s - 1; if ((unsigned)wx >= 56u) continue;
        acc += x[((size_t)(n * 128 + c) * 56 + hy) * 56 + wx] *
               wt[((size_t)(k * 128 + c) * 3 + r) * 3 + s];
      }
    }
  out[idx] = acc;
}

// ---------------- main implicit-GEMM MFMA conv (m97 structure) ----------------
// A = Wperm (256 x 1152), B = im2col(Xpad) (1152 x 100352), reduce order ck = rs*128 + c.
// K-step t (BK=32): rs = t>>2, c0 = (t&3)*32. Per-step row offset into padded NHWC:
#define BROFF(t) (((((t) >> 2) / 3) * 58 + (((t) >> 2) % 3)) * 128 + ((t) & 3) * 32)

__global__ __launch_bounds__(256, 4) void k_conv(const bf16_t* __restrict__ Xp,
                                                 const bf16_t* __restrict__ Wp,
                                                 const float* __restrict__ bias,
                                                 float* __restrict__ out) {
  // [buf][kc][row][8]: every 16B slot is one fragment k-chunk; gload_lds writes linear.
  __shared__ bf16_t Alds[2][4][128][8];   // 16 KB
  __shared__ bf16_t Blds[2][4][128][8];   // 16 KB
  const int tid = threadIdx.x;
  const int lane = tid & 63;
  const int wv = tid >> 6;
  const int m0 = ((int)blockIdx.x & 1) * 128;
  const int p0 = ((int)blockIdx.x >> 1) * 128;
  const int wr = wv >> 1, wc = wv & 1;

  // --- staging source pointers (per lane). Wave wv stages kc=wv for both A and B.
  const bf16_t* wA0 = Wp + (size_t)(m0 + lane) * 1152 + wv * 8;
  const bf16_t* wA1 = Wp + (size_t)(m0 + 64 + lane) * 1152 + wv * 8;
  int p_lo = p0 + lane, p_hi = p0 + 64 + lane;
  int ni_lo = p_lo / 3136, ni_hi = p_hi / 3136;
  int hw_lo = p_lo - ni_lo * 3136, hw_hi = p_hi - ni_hi * 3136;
  int hh_lo = hw_lo / 56, hh_hi = hw_hi / 56;
  int ww_lo = hw_lo - hh_lo * 56, ww_hi = hw_hi - hh_hi * 56;
  const bf16_t* xb0 = Xp + (((size_t)ni_lo * 58 + hh_lo) * 58 + ww_lo) * 128 + wv * 8;
  const bf16_t* xb1 = Xp + (((size_t)ni_hi * 58 + hh_hi) * 58 + ww_hi) * 128 + wv * 8;

#define STAGE(buf, tt) do {                                   \
    async16(wA0 + (tt) * 32, &Alds[buf][wv][0][0]);           \
    async16(wA1 + (tt) * 32, &Alds[buf][wv][64][0]);          \
    async16(xb0 + BROFF(tt), &Blds[buf][wv][0][0]);           \
    async16(xb1 + BROFF(tt), &Blds[buf][wv][64][0]);          \
  } while (0)

  f32x4 acc[4][4] = {};

  STAGE(0, 0);
  __syncthreads();          // compiler drains vmcnt before the barrier

#pragma unroll
  for (int t = 0; t < 36; ++t) {
    const int cur = t & 1;
    const int nxt = cur ^ 1;
    if (t + 1 < 36) STAGE(nxt, t + 1);   // issue next tile early; completes by barrier
    bf16x8 afr[4], bfr[4];
#pragma unroll
    for (int mi = 0; mi < 4; ++mi)
      afr[mi] = *(const bf16x8*)&Alds[cur][lane >> 4][wr * 64 + mi * 16 + (lane & 15)][0];
#pragma unroll
    for (int ni = 0; ni < 4; ++ni)
      bfr[ni] = *(const bf16x8*)&Blds[cur][lane >> 4][wc * 64 + ni * 16 + (lane & 15)][0];
#pragma unroll
    for (int mi = 0; mi < 4; ++mi)
#pragma unroll
      for (int ni = 0; ni < 4; ++ni)
        acc[mi][ni] = __builtin_amdgcn_mfma_f32_16x16x32_bf16(afr[mi], bfr[ni], acc[mi][ni], 0, 0, 0);
    __syncthreads();
  }
#undef STAGE

  // epilogue: D reg j of lane -> row=(l>>4)*4+j, col=l&15 (verified layout)
  float bv[4][4];
#pragma unroll
  for (int mi = 0; mi < 4; ++mi)
#pragma unroll
    for (int j = 0; j < 4; ++j)
      bv[mi][j] = bias[m0 + wr * 64 + mi * 16 + (lane >> 4) * 4 + j];

#pragma unroll
  for (int ni = 0; ni < 4; ++ni) {
    int p = p0 + wc * 64 + ni * 16 + (lane & 15);
    int nim = p / 3136;
    int hw2 = p - nim * 3136;
    float* ob = out + (size_t)nim * 802816 + hw2;
#pragma unroll
    for (int mi = 0; mi < 4; ++mi) {
      int rowb = m0 + wr * 64 + mi * 16 + (lane >> 4) * 4;
#pragma unroll
      for (int j = 0; j < 4; ++j)
        ob[(size_t)(rowb + j) * 3136] = acc[mi][ni][j] + bv[mi][j];
    }
  }
}

extern "C" void kernel_launch(void* const* d_in, const int* in_sizes, int n_in,
                              void* d_out, int out_size, void* d_ws, size_t ws_size,
                              hipStream_t stream) {
  const float* x  = (const float*)d_in[0];
  const float* wt = (const float*)d_in[1];
  const float* bs = (const float*)d_in[2];
  float* out = (float*)d_out;

  if (ws_size < WS_NEEDED) {     // safety net: direct fp32 conv
    k_naive<<<(25690112 + 255) / 256, 256, 0, stream>>>(x, wt, bs, out);
    return;
  }

  bf16_t* Xp = (bf16_t*)d_ws;
  bf16_t* Wp = (bf16_t*)((char*)d_ws + WPERM_OFF);

  k_xform<<<1856, 256, 0, stream>>>(x, Xp);                 // 32*58 padded rows
  k_wperm<<<1152, 256, 0, stream>>>(wt, Wp);                // 294912 / 256
  k_conv <<<1568, 256, 0, stream>>>(Xp, Wp, bs, out);       // 2 m-tiles * 784 n-tiles
}